// Round 12
// baseline (401.817 us; speedup 1.0000x reference)
//
#include <hip/hip_runtime.h>
#include <stdint.h>

#define DIN  512
#define DE   256
#define NC   1024
#define M_   65536
#define FLAGCAP 16384

typedef unsigned short u16;
typedef __attribute__((ext_vector_type(8))) short short8_t;   // 8 bf16
typedef __attribute__((ext_vector_type(4))) float f32x4_t;    // MFMA acc (16x16)
typedef __attribute__((ext_vector_type(16))) float f32x16_t;  // MFMA acc (32x32)

__device__ __forceinline__ float bf2f(u16 u) {
    unsigned x = ((unsigned)u) << 16; return __builtin_bit_cast(float, x);
}
__device__ __forceinline__ u16 f2bf(float f) {
    unsigned x = __builtin_bit_cast(unsigned, f);
    x += 0x7fffu + ((x >> 16) & 1u);
    return (u16)(x >> 16);
}
__device__ __forceinline__ void cvt8_hl(float4 a, float4 b, short8_t& h, short8_t& l) {
    float v[8] = {a.x,a.y,a.z,a.w, b.x,b.y,b.z,b.w};
#pragma unroll
    for (int j = 0; j < 8; ++j) {
        u16 hh = f2bf(v[j]);
        h[j] = (short)hh; l[j] = (short)f2bf(v[j] - bf2f(hh));
    }
}
__device__ __forceinline__ short8_t cvt8(float4 a, float4 b) {
    float v[8] = {a.x,a.y,a.z,a.w, b.x,b.y,b.z,b.w};
    short8_t h;
#pragma unroll
    for (int j = 0; j < 8; ++j) h[j] = (short)f2bf(v[j]);
    return h;
}

// ---------------------------------------------------------------------------
// K0: emb/Wd -> bf16 hi/lo; cnorm (f64); zero lossacc/flagcnt
// ---------------------------------------------------------------------------
__global__ void k_init(const float* __restrict__ emb, const float* __restrict__ Wd,
                       u16* __restrict__ embH, u16* __restrict__ embL,
                       u16* __restrict__ WdH,  u16* __restrict__ WdL,
                       float* __restrict__ cnorm,
                       float* __restrict__ lossacc, int* __restrict__ flagcnt) {
    int tid = blockIdx.x * 256 + threadIdx.x;           // 65536 threads
    for (int i = tid; i < DE * DIN; i += 65536) {
        float v = Wd[i]; u16 h = f2bf(v);
        WdH[i] = h; WdL[i] = f2bf(v - bf2f(h));
    }
    for (int i = tid; i < NC * DE; i += 65536) {
        float v = emb[i]; u16 h = f2bf(v);
        embH[i] = h; embL[i] = f2bf(v - bf2f(h));
    }
    if (tid < NC) {
        const float* c = emb + (size_t)tid * DE;
        double s = 0.0;
        for (int j = 0; j < DE; ++j) { double v = c[j]; s += v * v; }
        cnorm[tid] = (float)s;
    }
    if (tid < 16) lossacc[tid] = 0.f;
    if (tid == 16) *flagcnt = 0;
}

// ---------------------------------------------------------------------------
// K0b: P = E @ Wu^T in full f32. One-time -> z_q_out = gather of P rows.
// (133 KB static LDS — proves gfx950 workgroup LDS > 64 KB works here.)
// ---------------------------------------------------------------------------
__global__ __launch_bounds__(256, 1) void k_pup(
        const float* __restrict__ emb, const float* __restrict__ Wu,
        float* __restrict__ P) {
    __shared__ __align__(16) float le[64][260];
    __shared__ __align__(16) float lw[64][260];
    const int bi = blockIdx.x >> 3, bj = blockIdx.x & 7;
    const int t = threadIdx.x;
    {
        const int r = t >> 2, q = (t & 3) * 64;
        const float* se = emb + (size_t)(bi * 64 + r) * DE + q;
        const float* sw = Wu  + (size_t)(bj * 64 + r) * DE + q;
#pragma unroll
        for (int i = 0; i < 16; ++i) {
            *(float4*)&le[r][q + i * 4] = *(const float4*)(se + i * 4);
            *(float4*)&lw[r][q + i * 4] = *(const float4*)(sw + i * 4);
        }
    }
    __syncthreads();
    const int ci = (t >> 4) * 4, oi = (t & 15) * 4;
    float acc[4][4];
#pragma unroll
    for (int a = 0; a < 4; ++a)
#pragma unroll
        for (int b = 0; b < 4; ++b) acc[a][b] = 0.f;
    for (int k = 0; k < DE; k += 4) {
        float4 av[4], bv[4];
#pragma unroll
        for (int a = 0; a < 4; ++a) av[a] = *(const float4*)&le[ci + a][k];
#pragma unroll
        for (int b = 0; b < 4; ++b) bv[b] = *(const float4*)&lw[oi + b][k];
#pragma unroll
        for (int a = 0; a < 4; ++a)
#pragma unroll
            for (int b = 0; b < 4; ++b)
                acc[a][b] += av[a].x * bv[b].x + av[a].y * bv[b].y
                           + av[a].z * bv[b].z + av[a].w * bv[b].w;
    }
#pragma unroll
    for (int a = 0; a < 4; ++a)
#pragma unroll
        for (int b = 0; b < 4; ++b)
            P[(size_t)(bi * 64 + ci + a) * DIN + bj * 64 + oi + b] = acc[a][b];
}

// ---------------------------------------------------------------------------
// K1: FUSED z_e + argmin, BK=64 (halved iteration/barrier count vs r11).
// grid 512 x 256 thr (4 waves), 2 blocks/CU. LDS: aH/aL [2][128*72] hi/lo
// (72-u16 rows: same 4*lc%32 bank rotation as the proven 40-pad), 78.3 KB
// per block -> 156.7 KB/CU = exactly 2 blocks.
//
// Phase A (x2, mh=0/1): z_e. A = z-tile [128][64K] in LDS dbuf; B = Wd rows
// per-lane in regs (prefetched one kt ahead); 48 MFMA/wave/kt; 8 kt per mh.
// Phase B: argmin. Codes tile [128][64K] hi/lo staged per (ct,kt); 4 kt/ct,
// 48 MFMA/wave/kt; fused load+ds_write staging (round-5/8 proven form).
// ---------------------------------------------------------------------------
__global__ __launch_bounds__(256, 2) void k_fz(
        const float* __restrict__ Z,
        const u16* __restrict__ WdH, const u16* __restrict__ WdL,
        const u16* __restrict__ embH, const u16* __restrict__ embL,
        const float* __restrict__ cnorm,
        float* __restrict__ zeF,
        u16* __restrict__ codew, float* __restrict__ out_codef,
        int* __restrict__ flaglist,
        int* __restrict__ flagcnt, float* __restrict__ lossacc) {
    __shared__ __align__(16) u16 aH[2][128 * 72];
    __shared__ __align__(16) u16 aL[2][128 * 72];
    __shared__ float lCn[NC];
    __shared__ float lLoss[128];
    const int m0 = blockIdx.x * 128;
    const int t = threadIdx.x, lane = t & 63, wv = t >> 6;
    const int lc = lane & 31, hi = lane >> 5;
    const int zrow = m0 + wv * 32 + lc;

    for (int i = t; i < NC; i += 256) lCn[i] = cnorm[i];

    // ===================== Phase A: z_e (two M-halves, sequential) ========
    // staging coords: thread covers z-row t>>1, 32-f32 half (t&1)
    const int zsr = t >> 1, zss = (t & 1) * 32;
#define Z_LD(kt_) { \
        const float4* p = (const float4*)(Z + (size_t)(m0 + zsr) * DIN + (kt_) * 64 + zss); \
        zf[0] = p[0]; zf[1] = p[1]; zf[2] = p[2]; zf[3] = p[3]; \
        zf[4] = p[4]; zf[5] = p[5]; zf[6] = p[6]; zf[7] = p[7]; }
#define Z_WR(b_) { \
        short8_t h0, l0, h1, l1, h2, l2, h3, l3; \
        cvt8_hl(zf[0], zf[1], h0, l0); cvt8_hl(zf[2], zf[3], h1, l1); \
        cvt8_hl(zf[4], zf[5], h2, l2); cvt8_hl(zf[6], zf[7], h3, l3); \
        *(short8_t*)&aH[b_][zsr * 72 + zss]      = h0; \
        *(short8_t*)&aH[b_][zsr * 72 + zss + 8]  = h1; \
        *(short8_t*)&aH[b_][zsr * 72 + zss + 16] = h2; \
        *(short8_t*)&aH[b_][zsr * 72 + zss + 24] = h3; \
        *(short8_t*)&aL[b_][zsr * 72 + zss]      = l0; \
        *(short8_t*)&aL[b_][zsr * 72 + zss + 8]  = l1; \
        *(short8_t*)&aL[b_][zsr * 72 + zss + 16] = l2; \
        *(short8_t*)&aL[b_][zsr * 72 + zss + 24] = l3; }
#define WD_LD(kt_, H_, L_) { \
        _Pragma("unroll") for (int q = 0; q < 4; ++q) { \
            H_[q] = *(const short8_t*)(WdHr + (kt_) * 64 + q * 16 + hi * 8); \
            L_[q] = *(const short8_t*)(WdLr + (kt_) * 64 + q * 16 + hi * 8); } }

    for (int mh = 0; mh < 2; ++mh) {
        const int nb = mh * 128;
        const int wdrow = nb + wv * 32 + lc;
        const u16* WdHr = WdH + (size_t)wdrow * DIN;
        const u16* WdLr = WdL + (size_t)wdrow * DIN;

        float4 zf[8];
        short8_t wh[4], wl[4], nwh[4], nwl[4];
        Z_LD(0);
        WD_LD(0, wh, wl);
        __syncthreads();          // prior LDS consumers done
        Z_WR(0);
        __syncthreads();

        f32x16_t acc[4];
#pragma unroll
        for (int s = 0; s < 4; ++s)
#pragma unroll
            for (int r = 0; r < 16; ++r) acc[s][r] = 0.f;

        for (int kt = 0; kt < 8; ++kt) {
            if (kt < 7) { Z_LD(kt + 1); WD_LD(kt + 1, nwh, nwl); }
            const int buf = kt & 1;
#pragma unroll
            for (int ks = 0; ks < 4; ++ks) {
#pragma unroll
                for (int s = 0; s < 4; ++s) {
                    const int lo = (s * 32 + lc) * 72 + ks * 16 + hi * 8;
                    short8_t zh = *(const short8_t*)&aH[buf][lo];
                    short8_t zl = *(const short8_t*)&aL[buf][lo];
                    acc[s] = __builtin_amdgcn_mfma_f32_32x32x16_bf16(zh, wh[ks], acc[s], 0, 0, 0);
                    acc[s] = __builtin_amdgcn_mfma_f32_32x32x16_bf16(zh, wl[ks], acc[s], 0, 0, 0);
                    acc[s] = __builtin_amdgcn_mfma_f32_32x32x16_bf16(zl, wh[ks], acc[s], 0, 0, 0);
                }
            }
            if (kt < 7) {
                __syncthreads();
                Z_WR((kt + 1) & 1);
#pragma unroll
                for (int q = 0; q < 4; ++q) { wh[q] = nwh[q]; wl[q] = nwl[q]; }
                __syncthreads();
            }
        }
        // epilogue: acc[s][r] -> zeF[m0 + s*32+(r&3)+8*(r>>2)+4*hi][nb+wv*32+lc]
#pragma unroll
        for (int s = 0; s < 4; ++s)
#pragma unroll
            for (int r = 0; r < 16; ++r) {
                const int zr = m0 + s * 32 + (r & 3) + 8 * (r >> 2) + 4 * hi;
                zeF[(size_t)zr * DE + nb + wv * 32 + lc] = acc[s][r];
            }
    }
#undef Z_LD
#undef Z_WR
#undef WD_LD
    __syncthreads();   // drain zeF stores + free LDS for phase B

    // ===================== Phase B: argmin =================
    short8_t bh[16], bl[16];
    float rn = 0.f;
#pragma unroll
    for (int c = 0; c < 16; ++c) {
        const float4* zp = (const float4*)(zeF + (size_t)zrow * DE + c * 16 + hi * 8);
        float4 a = zp[0], b = zp[1];
        rn += a.x*a.x + a.y*a.y + a.z*a.z + a.w*a.w
            + b.x*b.x + b.y*b.y + b.z*b.z + b.w*b.w;
        cvt8_hl(a, b, bh[c], bl[c]);
    }
    rn += __shfl_xor(rn, 32, 64);

    // staging: 128 rows x 64 K hi+lo per (ct,kt); thread covers row idx>>3,
    // 8-u16 segment (idx&7)*8; 4 chunks/thread per array.
#define STAGE_E(ct_, kt_, b_) { \
        _Pragma("unroll") \
        for (int j = 0; j < 4; ++j) { \
            int idx = t + j * 256; \
            int row = idx >> 3, seg = (idx & 7) * 8; \
            size_t off = (size_t)((ct_) * 128 + row) * DE + (kt_) * 64 + seg; \
            uint4 vh = *(const uint4*)(embH + off); \
            uint4 vl = *(const uint4*)(embL + off); \
            *(uint4*)&aH[b_][row * 72 + seg] = vh; \
            *(uint4*)&aL[b_][row * 72 + seg] = vl; \
        } }

    float best = 3.4e38f, sec = 3.4e38f; int bidx = 0;
    STAGE_E(0, 0, 0);
    for (int ct = 0; ct < 8; ++ct) {
        f32x16_t acc[4];
#pragma unroll
        for (int s = 0; s < 4; ++s)
#pragma unroll
            for (int r = 0; r < 16; ++r) acc[s][r] = 0.f;
#pragma unroll
        for (int kt = 0; kt < 4; ++kt) {
            __syncthreads();
            if (kt < 3)      STAGE_E(ct, kt + 1, (kt + 1) & 1)
            else if (ct < 7) STAGE_E(ct + 1, 0, 0)
            const int buf = kt & 1;
#pragma unroll
            for (int ks = 0; ks < 4; ++ks) {
                const int c = kt * 4 + ks;
#pragma unroll
                for (int s = 0; s < 4; ++s) {
                    short8_t ah = *(const short8_t*)&aH[buf][(s * 32 + lc) * 72 + ks * 16 + hi * 8];
                    short8_t al = *(const short8_t*)&aL[buf][(s * 32 + lc) * 72 + ks * 16 + hi * 8];
                    acc[s] = __builtin_amdgcn_mfma_f32_32x32x16_bf16(ah, bh[c], acc[s], 0, 0, 0);
                    acc[s] = __builtin_amdgcn_mfma_f32_32x32x16_bf16(ah, bl[c], acc[s], 0, 0, 0);
                    acc[s] = __builtin_amdgcn_mfma_f32_32x32x16_bf16(al, bh[c], acc[s], 0, 0, 0);
                }
            }
        }
#pragma unroll
        for (int s = 0; s < 4; ++s)
#pragma unroll
            for (int r = 0; r < 16; ++r) {
                const int cidx = ct * 128 + s * 32 + (r & 3) + 8 * (r >> 2) + 4 * hi;
                float d = fmaf(-2.f, acc[s][r], lCn[cidx]);
                bool lt = d < best;
                sec  = lt ? best : fminf(sec, d);
                best = lt ? d : best;
                bidx = lt ? cidx : bidx;
            }
    }
#undef STAGE_E
    {
        float ob = __shfl_xor(best, 32, 64);
        float os = __shfl_xor(sec,  32, 64);
        int   oi = __shfl_xor(bidx, 32, 64);
        float ns = fminf(fminf(sec, os), fmaxf(best, ob));
        if (ob < best) { best = ob; bidx = oi; }
        sec = ns;
    }
    if (lane < 32) {
        codew[zrow] = (u16)bidx;
        out_codef[zrow] = (float)bidx;
        if (sec - best < 0.02f) {
            int pos = atomicAdd(flagcnt, 1);
            if (pos < FLAGCAP) flaglist[pos] = zrow;
        }
        lLoss[wv * 32 + lc] = rn + best;
    }
    __syncthreads();
    for (int str = 64; str > 0; str >>= 1) {
        if (t < str) lLoss[t] += lLoss[t + str];
        __syncthreads();
    }
    if (t == 0) atomicAdd(&lossacc[m0 >> 12], lLoss[0]);
}

// ---------------------------------------------------------------------------
// K2b: f64 exact re-argmin for flagged rows; updates codew AND out_code.
// ---------------------------------------------------------------------------
__global__ __launch_bounds__(256) void k_refine(
        const float* __restrict__ Z, const float* __restrict__ Wd,
        const float* __restrict__ emb,
        const int* __restrict__ flaglist, const int* __restrict__ flagcnt,
        u16* __restrict__ codew, float* __restrict__ out_codef) {
    __shared__ float  lz[DIN];
    __shared__ double lze[DE];
    __shared__ double ld[256];
    __shared__ int    li[256];
    int n = *flagcnt; if (n < 0) n = 0; if (n > FLAGCAP) n = FLAGCAP;
    int t = threadIdx.x;
    for (int f = blockIdx.x; f < n; f += gridDim.x) {
        int row = flaglist[f] & (M_ - 1);
        __syncthreads();
        for (int i = t; i < DIN; i += 256) lz[i] = Z[(size_t)row * DIN + i];
        __syncthreads();
        double a = 0.0;
        const float* wr = Wd + (size_t)t * DIN;
        for (int k = 0; k < DIN; ++k) a += (double)lz[k] * (double)wr[k];
        lze[t] = a;
        __syncthreads();
        double bd = 1e300; int bi = 0;
        for (int cc = 0; cc < 4; ++cc) {
            int c = cc * 256 + t;
            const float* cr = emb + (size_t)c * DE;
            double s = 0.0;
            for (int e = 0; e < DE; ++e) {
                double diff = lze[e] - (double)cr[e];
                s += diff * diff;
            }
            if (s < bd) { bd = s; bi = c; }
        }
        ld[t] = bd; li[t] = bi;
        __syncthreads();
        for (int str = 128; str > 0; str >>= 1) {
            if (t < str) {
                double od = ld[t + str]; int oi = li[t + str];
                if (od < ld[t] || (od == ld[t] && oi < li[t])) { ld[t] = od; li[t] = oi; }
            }
            __syncthreads();
        }
        if (t == 0) { codew[row] = (u16)li[0]; out_codef[row] = (float)li[0]; }
        __syncthreads();
    }
}

// ---------------------------------------------------------------------------
__global__ void k_loss(const float* __restrict__ lossacc,
                       float* __restrict__ out_commit, float* __restrict__ out_codebook) {
    int tid = threadIdx.x;
    if (tid < 16) {
        float v = lossacc[tid] * (1.f / 1048576.f);
        out_commit[tid] = v; out_codebook[tid] = v;
    }
}

// ---------------------------------------------------------------------------
// K3 (P path): z_q_out[row] = P[code[row]] — pure coalesced gather.
// Reads ONLY P (d_ws) and out_code (outside the z_q write region).
// ---------------------------------------------------------------------------
__global__ __launch_bounds__(256) void k_gather(
        const float* __restrict__ P, const float* __restrict__ out_code,
        float* __restrict__ out) {
    const int g = blockIdx.x * 256 + threadIdx.x;     // 524288 threads
    const float4* P4 = (const float4*)P;
    float4* O4 = (float4*)out;
    for (int u = g; u < M_ * 128; u += 524288) {
        const int row = u >> 7, seg = u & 127;
        const int c = (int)out_code[row] & (NC - 1);
        O4[(size_t)row * 128 + seg] = P4[(size_t)c * 128 + seg];
    }
}

// ---------------------------------------------------------------------------
// K3 (fallback, ws too small): z_q_out = emb[code] @ Wu^T, single bf16 term.
// ---------------------------------------------------------------------------
__global__ __launch_bounds__(512) void k_gemm3(
        const float* __restrict__ emb, const float* __restrict__ Wu,
        const float* __restrict__ out_code, float* __restrict__ out) {
    __shared__ __align__(16) u16 gA[128 * 264];   // 67.6 KB
    const int bz = blockIdx.x >> 1, nh = blockIdx.x & 1;
    const int m0 = bz * 128;
    const int t = threadIdx.x, lane = t & 63, wv = t >> 6;
    const int lr = lane & 15, lg = lane >> 4;
    {
        const int row = t >> 2, seg = (t & 3) * 64;
        const int code = (int)out_code[m0 + row] & (NC - 1);
        const float* src = emb + (size_t)code * DE + seg;
#pragma unroll
        for (int j = 0; j < 8; ++j) {
            const float4* p = (const float4*)(src + j * 8);
            *(short8_t*)&gA[row * 264 + seg + j * 8] = cvt8(p[0], p[1]);
        }
    }
    __syncthreads();

    const int nbase = nh * 256 + wv * 32;
    f32x4_t acc[8][2];
#pragma unroll
    for (int i = 0; i < 8; ++i)
#pragma unroll
        for (int j = 0; j < 2; ++j) acc[i][j] = (f32x4_t){0.f, 0.f, 0.f, 0.f};

#pragma unroll
    for (int kt = 0; kt < 8; ++kt) {
        const int k0 = kt * 32 + lg * 8;
        short8_t b0, b1;
        {
            const float4* p = (const float4*)(Wu + (size_t)(nbase + lr) * DE + k0);
            b0 = cvt8(p[0], p[1]);
            const float4* q = (const float4*)(Wu + (size_t)(nbase + 16 + lr) * DE + k0);
            b1 = cvt8(q[0], q[1]);
        }
#pragma unroll
        for (int mi = 0; mi < 8; ++mi) {
            short8_t a = *(const short8_t*)&gA[(mi * 16 + lr) * 264 + k0];
            acc[mi][0] = __builtin_amdgcn_mfma_f32_16x16x32_bf16(a, b0, acc[mi][0], 0, 0, 0);
            acc[mi][1] = __builtin_amdgcn_mfma_f32_16x16x32_bf16(a, b1, acc[mi][1], 0, 0, 0);
        }
    }
#pragma unroll
    for (int mi = 0; mi < 8; ++mi)
#pragma unroll
        for (int reg = 0; reg < 4; ++reg) {
            const int zr = m0 + mi * 16 + lg * 4 + reg;
            out[(size_t)zr * DIN + nbase + lr]      = acc[mi][0][reg];
            out[(size_t)zr * DIN + nbase + 16 + lr] = acc[mi][1][reg];
        }
}

// ---------------------------------------------------------------------------
extern "C" void kernel_launch(void* const* d_in, const int* in_sizes, int n_in,
                              void* d_out, int out_size, void* d_ws, size_t ws_size,
                              hipStream_t stream) {
    const float* Z   = (const float*)d_in[0];   // [16,4096,512] f32
    const float* E   = (const float*)d_in[1];   // [1024,256]    f32
    const float* Wd  = (const float*)d_in[2];   // [256,512]     f32
    const float* Wu  = (const float*)d_in[3];   // [512,256]     f32

    float* out       = (float*)d_out;           // f32 outputs, concat
    float* out_zq    = out;                     // [0, 33554432)
    float* out_com   = out + 33554432;          // 16
    float* out_cb    = out + 33554448;          // 16
    float* out_code  = out + 33554464;          // 65536
    float* out_ze    = out + 33620000;          // 16,777,216

    char* scr = (char*)d_out;
    u16*   embH     = (u16*)  (scr + 0);          // 524,288 B
    u16*   embL     = (u16*)  (scr + 524288);     // 524,288 B
    u16*   WdH      = (u16*)  (scr + 1048576);    // 262,144 B
    u16*   WdL      = (u16*)  (scr + 1310720);    // 262,144 B
    float* cnorm    = (float*)(scr + 1572864);    //   4,096 B
    u16*   codew    = (u16*)  (scr + 1839104);    // 131,072 B
    int*   flaglist = (int*)  (scr + 1970176);    //  65,536 B
    int*   flagcnt  = (int*)  (scr + 2035712);    //      64 B
    float* lossacc  = (float*)(scr + 2035776);    //      64 B
    (void)in_sizes; (void)n_in; (void)out_size;

    const bool useP = (ws_size >= (size_t)NC * DIN * sizeof(float));  // 2 MB
    float* P = (float*)d_ws;

    k_init  <<<256,  256, 0, stream>>>(E, Wd, embH, embL, WdH, WdL, cnorm,
                                       lossacc, flagcnt);
    if (useP)
        k_pup <<<128, 256, 0, stream>>>(E, Wu, P);
    k_fz    <<<512,  256, 0, stream>>>(Z, WdH, WdL, embH, embL, cnorm, out_ze,
                                       codew, out_code, flaglist, flagcnt, lossacc);
    k_refine<<<128,  256, 0, stream>>>(Z, Wd, E, flaglist, flagcnt, codew, out_code);
    k_loss  <<<1,    64,  0, stream>>>(lossacc, out_com, out_cb);
    if (useP)
        k_gather<<<2048, 256, 0, stream>>>(P, out_code, out_zq);
    else
        k_gemm3 <<<1024, 512, 0, stream>>>(E, Wu, out_code, out_zq);
}

// Round 13
// 336.526 us; speedup vs baseline: 1.1940x; 1.1940x over previous
//
#include <hip/hip_runtime.h>
#include <stdint.h>

#define DIN  512
#define DE   256
#define NC   1024
#define M_   65536
#define FLAGCAP 16384

typedef unsigned short u16;
typedef __attribute__((ext_vector_type(8))) short short8_t;   // 8 bf16
typedef __attribute__((ext_vector_type(4))) float f32x4_t;    // MFMA acc (16x16)
typedef __attribute__((ext_vector_type(16))) float f32x16_t;  // MFMA acc (32x32)

__device__ __forceinline__ float bf2f(u16 u) {
    unsigned x = ((unsigned)u) << 16; return __builtin_bit_cast(float, x);
}
__device__ __forceinline__ u16 f2bf(float f) {
    unsigned x = __builtin_bit_cast(unsigned, f);
    x += 0x7fffu + ((x >> 16) & 1u);
    return (u16)(x >> 16);
}
__device__ __forceinline__ void cvt8_hl(float4 a, float4 b, short8_t& h, short8_t& l) {
    float v[8] = {a.x,a.y,a.z,a.w, b.x,b.y,b.z,b.w};
#pragma unroll
    for (int j = 0; j < 8; ++j) {
        u16 hh = f2bf(v[j]);
        h[j] = (short)hh; l[j] = (short)f2bf(v[j] - bf2f(hh));
    }
}
__device__ __forceinline__ short8_t cvt8(float4 a, float4 b) {
    float v[8] = {a.x,a.y,a.z,a.w, b.x,b.y,b.z,b.w};
    short8_t h;
#pragma unroll
    for (int j = 0; j < 8; ++j) h[j] = (short)f2bf(v[j]);
    return h;
}

// async global->LDS, 16B per lane. dest must be wave-uniform base + lane*16.
__device__ __forceinline__ void gl_lds16(const u16* g, u16* l) {
    __builtin_amdgcn_global_load_lds(
        (const __attribute__((address_space(1))) unsigned int*)g,
        (__attribute__((address_space(3))) unsigned int*)l, 16, 0, 0);
}

// ---------------------------------------------------------------------------
// K0: emb/Wd -> bf16 hi/lo; cnorm (f64); zero lossacc/flagcnt
// ---------------------------------------------------------------------------
__global__ void k_init(const float* __restrict__ emb, const float* __restrict__ Wd,
                       u16* __restrict__ embH, u16* __restrict__ embL,
                       u16* __restrict__ WdH,  u16* __restrict__ WdL,
                       float* __restrict__ cnorm,
                       float* __restrict__ lossacc, int* __restrict__ flagcnt) {
    int tid = blockIdx.x * 256 + threadIdx.x;           // 65536 threads
    for (int i = tid; i < DE * DIN; i += 65536) {
        float v = Wd[i]; u16 h = f2bf(v);
        WdH[i] = h; WdL[i] = f2bf(v - bf2f(h));
    }
    for (int i = tid; i < NC * DE; i += 65536) {
        float v = emb[i]; u16 h = f2bf(v);
        embH[i] = h; embL[i] = f2bf(v - bf2f(h));
    }
    if (tid < NC) {
        const float* c = emb + (size_t)tid * DE;
        double s = 0.0;
        for (int j = 0; j < DE; ++j) { double v = c[j]; s += v * v; }
        cnorm[tid] = (float)s;
    }
    if (tid < 16) lossacc[tid] = 0.f;
    if (tid == 16) *flagcnt = 0;
}

// ---------------------------------------------------------------------------
// K0b: P = E @ Wu^T in full f32. One-time -> z_q_out = gather of P rows.
// ---------------------------------------------------------------------------
__global__ __launch_bounds__(256, 1) void k_pup(
        const float* __restrict__ emb, const float* __restrict__ Wu,
        float* __restrict__ P) {
    __shared__ __align__(16) float le[64][260];
    __shared__ __align__(16) float lw[64][260];
    const int bi = blockIdx.x >> 3, bj = blockIdx.x & 7;
    const int t = threadIdx.x;
    {
        const int r = t >> 2, q = (t & 3) * 64;
        const float* se = emb + (size_t)(bi * 64 + r) * DE + q;
        const float* sw = Wu  + (size_t)(bj * 64 + r) * DE + q;
#pragma unroll
        for (int i = 0; i < 16; ++i) {
            *(float4*)&le[r][q + i * 4] = *(const float4*)(se + i * 4);
            *(float4*)&lw[r][q + i * 4] = *(const float4*)(sw + i * 4);
        }
    }
    __syncthreads();
    const int ci = (t >> 4) * 4, oi = (t & 15) * 4;
    float acc[4][4];
#pragma unroll
    for (int a = 0; a < 4; ++a)
#pragma unroll
        for (int b = 0; b < 4; ++b) acc[a][b] = 0.f;
    for (int k = 0; k < DE; k += 4) {
        float4 av[4], bv[4];
#pragma unroll
        for (int a = 0; a < 4; ++a) av[a] = *(const float4*)&le[ci + a][k];
#pragma unroll
        for (int b = 0; b < 4; ++b) bv[b] = *(const float4*)&lw[oi + b][k];
#pragma unroll
        for (int a = 0; a < 4; ++a)
#pragma unroll
            for (int b = 0; b < 4; ++b)
                acc[a][b] += av[a].x * bv[b].x + av[a].y * bv[b].y
                           + av[a].z * bv[b].z + av[a].w * bv[b].w;
    }
#pragma unroll
    for (int a = 0; a < 4; ++a)
#pragma unroll
        for (int b = 0; b < 4; ++b)
            P[(size_t)(bi * 64 + ci + a) * DIN + bj * 64 + oi + b] = acc[a][b];
}

// ---------------------------------------------------------------------------
// K1: FUSED z_e + argmin, BK=32 (round-11 proven structure).
// grid 512 x 256 thr (4 waves), 2 blocks/CU. LDS aH/aL [2][128*40].
//
// Phase A (x2, mh): z_e, reg-staged (f32->hi/lo cvt required), unchanged.
// Phase B: argmin with ASYNC staging: global_load_lds 16B/lane, linear
// [128][32]-u16 view of the same buffers (first 4096 u16 of each), granule
// XOR swizzle g_p = g_log ^ ((row>>1)&3) applied to BOTH global source and
// read offset (same involution, rule #21) -> conflict-free reads (8 dw/bank
// floor). Wave issues 4 async loads then goes straight to MFMAs; the single
// barrier/iter drains vmcnt.
// ---------------------------------------------------------------------------
__global__ __launch_bounds__(256, 2) void k_fz(
        const float* __restrict__ Z,
        const u16* __restrict__ WdH, const u16* __restrict__ WdL,
        const u16* __restrict__ embH, const u16* __restrict__ embL,
        const float* __restrict__ cnorm,
        float* __restrict__ zeF,
        u16* __restrict__ codew, float* __restrict__ out_codef,
        int* __restrict__ flaglist,
        int* __restrict__ flagcnt, float* __restrict__ lossacc) {
    __shared__ __align__(16) u16 aH[2][128 * 40];
    __shared__ __align__(16) u16 aL[2][128 * 40];
    __shared__ float lCn[NC];
    __shared__ float lLoss[128];
    const int m0 = blockIdx.x * 128;
    const int t = threadIdx.x, lane = t & 63, wv = t >> 6;
    const int lc = lane & 31, hi = lane >> 5;
    const int zrow = m0 + wv * 32 + lc;
    const int zsr = t >> 1, zss = (t & 1) * 16;   // phase-A staging coords

    for (int i = t; i < NC; i += 256) lCn[i] = cnorm[i];

    // ===================== Phase A: z_e (two M-halves, sequential) ========
#define Z_LD(kt_) { \
        const float4* p = (const float4*)(Z + (size_t)(m0 + zsr) * DIN + (kt_) * 32 + zss); \
        zf[0] = p[0]; zf[1] = p[1]; zf[2] = p[2]; zf[3] = p[3]; }
#define Z_WR(b_) { \
        short8_t h0, l0, h1, l1; \
        cvt8_hl(zf[0], zf[1], h0, l0); cvt8_hl(zf[2], zf[3], h1, l1); \
        *(short8_t*)&aH[b_][zsr * 40 + zss]     = h0; \
        *(short8_t*)&aH[b_][zsr * 40 + zss + 8] = h1; \
        *(short8_t*)&aL[b_][zsr * 40 + zss]     = l0; \
        *(short8_t*)&aL[b_][zsr * 40 + zss + 8] = l1; }
#define WD_LD(kt_, H_, L_) { \
        H_[0] = *(const short8_t*)(WdHr + (kt_) * 32 + hi * 8); \
        H_[1] = *(const short8_t*)(WdHr + (kt_) * 32 + 16 + hi * 8); \
        L_[0] = *(const short8_t*)(WdLr + (kt_) * 32 + hi * 8); \
        L_[1] = *(const short8_t*)(WdLr + (kt_) * 32 + 16 + hi * 8); }

    for (int mh = 0; mh < 2; ++mh) {
        const int nb = mh * 128;
        const int wdrow = nb + wv * 32 + lc;
        const u16* WdHr = WdH + (size_t)wdrow * DIN;
        const u16* WdLr = WdL + (size_t)wdrow * DIN;

        float4 zf[4];
        short8_t wh[2], wl[2], nwh[2], nwl[2];
        Z_LD(0);
        WD_LD(0, wh, wl);
        __syncthreads();          // prior LDS consumers done
        Z_WR(0);
        __syncthreads();

        f32x16_t acc[4];
#pragma unroll
        for (int s = 0; s < 4; ++s)
#pragma unroll
            for (int r = 0; r < 16; ++r) acc[s][r] = 0.f;

        for (int kt = 0; kt < 16; ++kt) {
            if (kt < 15) { Z_LD(kt + 1); WD_LD(kt + 1, nwh, nwl); }
            const int buf = kt & 1;
#pragma unroll
            for (int ks = 0; ks < 2; ++ks) {
#pragma unroll
                for (int s = 0; s < 4; ++s) {
                    const int lo = (s * 32 + lc) * 40 + ks * 16 + hi * 8;
                    short8_t zh = *(const short8_t*)&aH[buf][lo];
                    short8_t zl = *(const short8_t*)&aL[buf][lo];
                    acc[s] = __builtin_amdgcn_mfma_f32_32x32x16_bf16(zh, wh[ks], acc[s], 0, 0, 0);
                    acc[s] = __builtin_amdgcn_mfma_f32_32x32x16_bf16(zh, wl[ks], acc[s], 0, 0, 0);
                    acc[s] = __builtin_amdgcn_mfma_f32_32x32x16_bf16(zl, wh[ks], acc[s], 0, 0, 0);
                }
            }
            if (kt < 15) {
                __syncthreads();
                Z_WR((kt + 1) & 1);
                wh[0] = nwh[0]; wh[1] = nwh[1];
                wl[0] = nwl[0]; wl[1] = nwl[1];
                __syncthreads();
            }
        }
        // epilogue: acc[s][r] -> zeF[m0 + s*32+(r&3)+8*(r>>2)+4*hi][nb+wv*32+lc]
#pragma unroll
        for (int s = 0; s < 4; ++s)
#pragma unroll
            for (int r = 0; r < 16; ++r) {
                const int zr = m0 + s * 32 + (r & 3) + 8 * (r >> 2) + 4 * hi;
                zeF[(size_t)zr * DE + nb + wv * 32 + lc] = acc[s][r];
            }
    }
#undef Z_LD
#undef Z_WR
#undef WD_LD
    __syncthreads();   // drain zeF stores + free LDS for phase B

    // ===================== Phase B: argmin (async staged) =================
    short8_t bh[16], bl[16];
    float rn = 0.f;
#pragma unroll
    for (int c = 0; c < 16; ++c) {
        const float4* zp = (const float4*)(zeF + (size_t)zrow * DE + c * 16 + hi * 8);
        float4 a = zp[0], b = zp[1];
        rn += a.x*a.x + a.y*a.y + a.z*a.z + a.w*a.w
            + b.x*b.x + b.y*b.y + b.z*b.z + b.w*b.w;
        cvt8_hl(a, b, bh[c], bl[c]);
    }
    rn += __shfl_xor(rn, 32, 64);

    // async staging: granule p = t + j*256 -> LDS byte p*16 (linear per wave,
    // unpadded [128][32]-u16 rows); global source uses swizzled g_log.
#define STAGE_GL(ct_, kt_) { \
        _Pragma("unroll") \
        for (int j = 0; j < 2; ++j) { \
            int p = t + j * 256; \
            int row = p >> 2, gp = p & 3; \
            int gl = gp ^ ((row >> 1) & 3); \
            size_t off = (size_t)((ct_) * 128 + row) * DE + (kt_) * 32 + gl * 8; \
            gl_lds16(embH + off, &aH[bufn][p * 8]); \
            gl_lds16(embL + off, &aL[bufn][p * 8]); \
        } }

    const int rho = (lc >> 1) & 3;   // read-side swizzle (uniform over s)

    float best = 3.4e38f, sec = 3.4e38f; int bidx = 0;
    {
        const int bufn = 0;
        STAGE_GL(0, 0);
    }
    for (int ct = 0; ct < 8; ++ct) {
        f32x16_t acc[4];
#pragma unroll
        for (int s = 0; s < 4; ++s)
#pragma unroll
            for (int r = 0; r < 16; ++r) acc[s][r] = 0.f;
#pragma unroll
        for (int kt = 0; kt < 8; ++kt) {
            __syncthreads();      // drains vmcnt -> buffer (kt&1) ready
            {
                const int bufn = (kt + 1) & 1;
                if (kt < 7)      STAGE_GL(ct, kt + 1)
                else if (ct < 7) STAGE_GL(ct + 1, 0)
            }
            const int buf = kt & 1;
#pragma unroll
            for (int ks = 0; ks < 2; ++ks) {
                const int c = kt * 2 + ks;
#pragma unroll
                for (int s = 0; s < 4; ++s) {
                    const int lo = (s * 32 + lc) * 32 + (((ks * 2 + hi) ^ rho) << 3);
                    short8_t ah = *(const short8_t*)&aH[buf][lo];
                    short8_t al = *(const short8_t*)&aL[buf][lo];
                    acc[s] = __builtin_amdgcn_mfma_f32_32x32x16_bf16(ah, bh[c], acc[s], 0, 0, 0);
                    acc[s] = __builtin_amdgcn_mfma_f32_32x32x16_bf16(ah, bl[c], acc[s], 0, 0, 0);
                    acc[s] = __builtin_amdgcn_mfma_f32_32x32x16_bf16(al, bh[c], acc[s], 0, 0, 0);
                }
            }
        }
#pragma unroll
        for (int s = 0; s < 4; ++s)
#pragma unroll
            for (int r = 0; r < 16; ++r) {
                const int cidx = ct * 128 + s * 32 + (r & 3) + 8 * (r >> 2) + 4 * hi;
                float d = fmaf(-2.f, acc[s][r], lCn[cidx]);
                bool lt = d < best;
                sec  = lt ? best : fminf(sec, d);
                best = lt ? d : best;
                bidx = lt ? cidx : bidx;
            }
    }
#undef STAGE_GL
    {
        float ob = __shfl_xor(best, 32, 64);
        float os = __shfl_xor(sec,  32, 64);
        int   oi = __shfl_xor(bidx, 32, 64);
        float ns = fminf(fminf(sec, os), fmaxf(best, ob));
        if (ob < best) { best = ob; bidx = oi; }
        sec = ns;
    }
    if (lane < 32) {
        codew[zrow] = (u16)bidx;
        out_codef[zrow] = (float)bidx;
        if (sec - best < 0.02f) {
            int pos = atomicAdd(flagcnt, 1);
            if (pos < FLAGCAP) flaglist[pos] = zrow;
        }
        lLoss[wv * 32 + lc] = rn + best;
    }
    __syncthreads();
    for (int str = 64; str > 0; str >>= 1) {
        if (t < str) lLoss[t] += lLoss[t + str];
        __syncthreads();
    }
    if (t == 0) atomicAdd(&lossacc[m0 >> 12], lLoss[0]);
}

// ---------------------------------------------------------------------------
// K2b: f64 exact re-argmin for flagged rows; updates codew AND out_code.
// Block 0 also emits the loss outputs (lossacc is final after k_fz).
// ---------------------------------------------------------------------------
__global__ __launch_bounds__(256) void k_refine(
        const float* __restrict__ Z, const float* __restrict__ Wd,
        const float* __restrict__ emb,
        const int* __restrict__ flaglist, const int* __restrict__ flagcnt,
        u16* __restrict__ codew, float* __restrict__ out_codef,
        const float* __restrict__ lossacc,
        float* __restrict__ out_commit, float* __restrict__ out_codebook) {
    __shared__ float  lz[DIN];
    __shared__ double lze[DE];
    __shared__ double ld[256];
    __shared__ int    li[256];
    int t = threadIdx.x;
    if (blockIdx.x == 0 && t < 16) {
        float v = lossacc[t] * (1.f / 1048576.f);
        out_commit[t] = v; out_codebook[t] = v;
    }
    int n = *flagcnt; if (n < 0) n = 0; if (n > FLAGCAP) n = FLAGCAP;
    for (int f = blockIdx.x; f < n; f += gridDim.x) {
        int row = flaglist[f] & (M_ - 1);
        __syncthreads();
        for (int i = t; i < DIN; i += 256) lz[i] = Z[(size_t)row * DIN + i];
        __syncthreads();
        double a = 0.0;
        const float* wr = Wd + (size_t)t * DIN;
        for (int k = 0; k < DIN; ++k) a += (double)lz[k] * (double)wr[k];
        lze[t] = a;
        __syncthreads();
        double bd = 1e300; int bi = 0;
        for (int cc = 0; cc < 4; ++cc) {
            int c = cc * 256 + t;
            const float* cr = emb + (size_t)c * DE;
            double s = 0.0;
            for (int e = 0; e < DE; ++e) {
                double diff = lze[e] - (double)cr[e];
                s += diff * diff;
            }
            if (s < bd) { bd = s; bi = c; }
        }
        ld[t] = bd; li[t] = bi;
        __syncthreads();
        for (int str = 128; str > 0; str >>= 1) {
            if (t < str) {
                double od = ld[t + str]; int oi = li[t + str];
                if (od < ld[t] || (od == ld[t] && oi < li[t])) { ld[t] = od; li[t] = oi; }
            }
            __syncthreads();
        }
        if (t == 0) { codew[row] = (u16)li[0]; out_codef[row] = (float)li[0]; }
        __syncthreads();
    }
}

// ---------------------------------------------------------------------------
// K3 (P path): z_q_out[row] = P[code[row]] — pure coalesced gather.
// Reads ONLY P (d_ws) and out_code (outside the z_q write region).
// ---------------------------------------------------------------------------
__global__ __launch_bounds__(256) void k_gather(
        const float* __restrict__ P, const float* __restrict__ out_code,
        float* __restrict__ out) {
    const int g = blockIdx.x * 256 + threadIdx.x;     // 524288 threads
    const float4* P4 = (const float4*)P;
    float4* O4 = (float4*)out;
    for (int u = g; u < M_ * 128; u += 524288) {
        const int row = u >> 7, seg = u & 127;
        const int c = (int)out_code[row] & (NC - 1);
        O4[(size_t)row * 128 + seg] = P4[(size_t)c * 128 + seg];
    }
}

// ---------------------------------------------------------------------------
// K3 (fallback, ws too small): z_q_out = emb[code] @ Wu^T, single bf16 term.
// ---------------------------------------------------------------------------
__global__ __launch_bounds__(512) void k_gemm3(
        const float* __restrict__ emb, const float* __restrict__ Wu,
        const float* __restrict__ out_code, float* __restrict__ out) {
    __shared__ __align__(16) u16 gA[128 * 264];   // 67.6 KB
    const int bz = blockIdx.x >> 1, nh = blockIdx.x & 1;
    const int m0 = bz * 128;
    const int t = threadIdx.x, lane = t & 63, wv = t >> 6;
    const int lr = lane & 15, lg = lane >> 4;
    {
        const int row = t >> 2, seg = (t & 3) * 64;
        const int code = (int)out_code[m0 + row] & (NC - 1);
        const float* src = emb + (size_t)code * DE + seg;
#pragma unroll
        for (int j = 0; j < 8; ++j) {
            const float4* p = (const float4*)(src + j * 8);
            *(short8_t*)&gA[row * 264 + seg + j * 8] = cvt8(p[0], p[1]);
        }
    }
    __syncthreads();

    const int nbase = nh * 256 + wv * 32;
    f32x4_t acc[8][2];
#pragma unroll
    for (int i = 0; i < 8; ++i)
#pragma unroll
        for (int j = 0; j < 2; ++j) acc[i][j] = (f32x4_t){0.f, 0.f, 0.f, 0.f};

#pragma unroll
    for (int kt = 0; kt < 8; ++kt) {
        const int k0 = kt * 32 + lg * 8;
        short8_t b0, b1;
        {
            const float4* p = (const float4*)(Wu + (size_t)(nbase + lr) * DE + k0);
            b0 = cvt8(p[0], p[1]);
            const float4* q = (const float4*)(Wu + (size_t)(nbase + 16 + lr) * DE + k0);
            b1 = cvt8(q[0], q[1]);
        }
#pragma unroll
        for (int mi = 0; mi < 8; ++mi) {
            short8_t a = *(const short8_t*)&gA[(mi * 16 + lr) * 264 + k0];
            acc[mi][0] = __builtin_amdgcn_mfma_f32_16x16x32_bf16(a, b0, acc[mi][0], 0, 0, 0);
            acc[mi][1] = __builtin_amdgcn_mfma_f32_16x16x32_bf16(a, b1, acc[mi][1], 0, 0, 0);
        }
    }
#pragma unroll
    for (int mi = 0; mi < 8; ++mi)
#pragma unroll
        for (int reg = 0; reg < 4; ++reg) {
            const int zr = m0 + mi * 16 + lg * 4 + reg;
            out[(size_t)zr * DIN + nbase + lr]      = acc[mi][0][reg];
            out[(size_t)zr * DIN + nbase + 16 + lr] = acc[mi][1][reg];
        }
}

// ---------------------------------------------------------------------------
extern "C" void kernel_launch(void* const* d_in, const int* in_sizes, int n_in,
                              void* d_out, int out_size, void* d_ws, size_t ws_size,
                              hipStream_t stream) {
    const float* Z   = (const float*)d_in[0];   // [16,4096,512] f32
    const float* E   = (const float*)d_in[1];   // [1024,256]    f32
    const float* Wd  = (const float*)d_in[2];   // [256,512]     f32
    const float* Wu  = (const float*)d_in[3];   // [512,256]     f32

    float* out       = (float*)d_out;           // f32 outputs, concat
    float* out_zq    = out;                     // [0, 33554432)
    float* out_com   = out + 33554432;          // 16
    float* out_cb    = out + 33554448;          // 16
    float* out_code  = out + 33554464;          // 65536
    float* out_ze    = out + 33620000;          // 16,777,216

    char* scr = (char*)d_out;
    u16*   embH     = (u16*)  (scr + 0);          // 524,288 B
    u16*   embL     = (u16*)  (scr + 524288);     // 524,288 B
    u16*   WdH      = (u16*)  (scr + 1048576);    // 262,144 B
    u16*   WdL      = (u16*)  (scr + 1310720);    // 262,144 B
    float* cnorm    = (float*)(scr + 1572864);    //   4,096 B
    u16*   codew    = (u16*)  (scr + 1839104);    // 131,072 B
    int*   flaglist = (int*)  (scr + 1970176);    //  65,536 B
    int*   flagcnt  = (int*)  (scr + 2035712);    //      64 B
    float* lossacc  = (float*)(scr + 2035776);    //      64 B
    (void)in_sizes; (void)n_in; (void)out_size;

    const bool useP = (ws_size >= (size_t)NC * DIN * sizeof(float));  // 2 MB
    float* P = (float*)d_ws;

    k_init  <<<256,  256, 0, stream>>>(E, Wd, embH, embL, WdH, WdL, cnorm,
                                       lossacc, flagcnt);
    if (useP)
        k_pup <<<128, 256, 0, stream>>>(E, Wu, P);
    k_fz    <<<512,  256, 0, stream>>>(Z, WdH, WdL, embH, embL, cnorm, out_ze,
                                       codew, out_code, flaglist, flagcnt, lossacc);
    k_refine<<<128,  256, 0, stream>>>(Z, Wd, E, flaglist, flagcnt, codew, out_code,
                                       lossacc, out_com, out_cb);
    if (useP)
        k_gather<<<2048, 256, 0, stream>>>(P, out_code, out_zq);
    else
        k_gemm3 <<<1024, 512, 0, stream>>>(E, Wu, out_code, out_zq);
}

// Round 14
// 325.049 us; speedup vs baseline: 1.2362x; 1.0353x over previous
//
#include <hip/hip_runtime.h>
#include <stdint.h>

#define DIN  512
#define DE   256
#define NC   1024
#define M_   65536
#define FLAGCAP 16384

typedef unsigned short u16;
typedef __attribute__((ext_vector_type(8))) short short8_t;   // 8 bf16
typedef __attribute__((ext_vector_type(4))) float f32x4_t;    // MFMA acc (16x16)
typedef __attribute__((ext_vector_type(16))) float f32x16_t;  // MFMA acc (32x32)

__device__ __forceinline__ float bf2f(u16 u) {
    unsigned x = ((unsigned)u) << 16; return __builtin_bit_cast(float, x);
}
__device__ __forceinline__ u16 f2bf(float f) {
    unsigned x = __builtin_bit_cast(unsigned, f);
    x += 0x7fffu + ((x >> 16) & 1u);
    return (u16)(x >> 16);
}
__device__ __forceinline__ void cvt8_hl(float4 a, float4 b, short8_t& h, short8_t& l) {
    float v[8] = {a.x,a.y,a.z,a.w, b.x,b.y,b.z,b.w};
#pragma unroll
    for (int j = 0; j < 8; ++j) {
        u16 hh = f2bf(v[j]);
        h[j] = (short)hh; l[j] = (short)f2bf(v[j] - bf2f(hh));
    }
}
__device__ __forceinline__ short8_t cvt8(float4 a, float4 b) {
    float v[8] = {a.x,a.y,a.z,a.w, b.x,b.y,b.z,b.w};
    short8_t h;
#pragma unroll
    for (int j = 0; j < 8; ++j) h[j] = (short)f2bf(v[j]);
    return h;
}

// async global->LDS, 16B per lane. dest must be wave-uniform base + lane*16.
__device__ __forceinline__ void gl_lds16(const u16* g, u16* l) {
    __builtin_amdgcn_global_load_lds(
        (const __attribute__((address_space(1))) unsigned int*)g,
        (__attribute__((address_space(3))) unsigned int*)l, 16, 0, 0);
}

// ---------------------------------------------------------------------------
// K0: emb/Wd -> bf16 hi/lo; cnorm (f64); zero lossacc/flagcnt
// ---------------------------------------------------------------------------
__global__ void k_init(const float* __restrict__ emb, const float* __restrict__ Wd,
                       u16* __restrict__ embH, u16* __restrict__ embL,
                       u16* __restrict__ WdH,  u16* __restrict__ WdL,
                       float* __restrict__ cnorm,
                       float* __restrict__ lossacc, int* __restrict__ flagcnt) {
    int tid = blockIdx.x * 256 + threadIdx.x;           // 65536 threads
    for (int i = tid; i < DE * DIN; i += 65536) {
        float v = Wd[i]; u16 h = f2bf(v);
        WdH[i] = h; WdL[i] = f2bf(v - bf2f(h));
    }
    for (int i = tid; i < NC * DE; i += 65536) {
        float v = emb[i]; u16 h = f2bf(v);
        embH[i] = h; embL[i] = f2bf(v - bf2f(h));
    }
    if (tid < NC) {
        const float* c = emb + (size_t)tid * DE;
        double s = 0.0;
        for (int j = 0; j < DE; ++j) { double v = c[j]; s += v * v; }
        cnorm[tid] = (float)s;
    }
    if (tid < 16) lossacc[tid] = 0.f;
    if (tid == 16) *flagcnt = 0;
}

// ---------------------------------------------------------------------------
// K0b: P = E @ Wu^T in full f32. One-time -> z_q_out = gather of P rows.
// ---------------------------------------------------------------------------
__global__ __launch_bounds__(256, 1) void k_pup(
        const float* __restrict__ emb, const float* __restrict__ Wu,
        float* __restrict__ P) {
    __shared__ __align__(16) float le[64][260];
    __shared__ __align__(16) float lw[64][260];
    const int bi = blockIdx.x >> 3, bj = blockIdx.x & 7;
    const int t = threadIdx.x;
    {
        const int r = t >> 2, q = (t & 3) * 64;
        const float* se = emb + (size_t)(bi * 64 + r) * DE + q;
        const float* sw = Wu  + (size_t)(bj * 64 + r) * DE + q;
#pragma unroll
        for (int i = 0; i < 16; ++i) {
            *(float4*)&le[r][q + i * 4] = *(const float4*)(se + i * 4);
            *(float4*)&lw[r][q + i * 4] = *(const float4*)(sw + i * 4);
        }
    }
    __syncthreads();
    const int ci = (t >> 4) * 4, oi = (t & 15) * 4;
    float acc[4][4];
#pragma unroll
    for (int a = 0; a < 4; ++a)
#pragma unroll
        for (int b = 0; b < 4; ++b) acc[a][b] = 0.f;
    for (int k = 0; k < DE; k += 4) {
        float4 av[4], bv[4];
#pragma unroll
        for (int a = 0; a < 4; ++a) av[a] = *(const float4*)&le[ci + a][k];
#pragma unroll
        for (int b = 0; b < 4; ++b) bv[b] = *(const float4*)&lw[oi + b][k];
#pragma unroll
        for (int a = 0; a < 4; ++a)
#pragma unroll
            for (int b = 0; b < 4; ++b)
                acc[a][b] += av[a].x * bv[b].x + av[a].y * bv[b].y
                           + av[a].z * bv[b].z + av[a].w * bv[b].w;
    }
#pragma unroll
    for (int a = 0; a < 4; ++a)
#pragma unroll
        for (int b = 0; b < 4; ++b)
            P[(size_t)(bi * 64 + ci + a) * DIN + bj * 64 + oi + b] = acc[a][b];
}

// ---------------------------------------------------------------------------
// K1: FUSED z_e + argmin, BK=32 (round-13 proven structure + T5 setprio).
// grid 512 x 256 thr (4 waves), 2 blocks/CU. LDS aH/aL [2][128*40].
// setprio(1) around the MFMA clusters: the 2 independent blocks per CU sit
// at skewed phases, so MFMA-entering waves preempt the other block's
// staging/VALU waves (T5 mechanism; m191 case, not m190 lockstep).
// ---------------------------------------------------------------------------
__global__ __launch_bounds__(256, 2) void k_fz(
        const float* __restrict__ Z,
        const u16* __restrict__ WdH, const u16* __restrict__ WdL,
        const u16* __restrict__ embH, const u16* __restrict__ embL,
        const float* __restrict__ cnorm,
        float* __restrict__ zeF,
        u16* __restrict__ codew, float* __restrict__ out_codef,
        int* __restrict__ flaglist,
        int* __restrict__ flagcnt, float* __restrict__ lossacc) {
    __shared__ __align__(16) u16 aH[2][128 * 40];
    __shared__ __align__(16) u16 aL[2][128 * 40];
    __shared__ float lCn[NC];
    __shared__ float lLoss[128];
    const int m0 = blockIdx.x * 128;
    const int t = threadIdx.x, lane = t & 63, wv = t >> 6;
    const int lc = lane & 31, hi = lane >> 5;
    const int zrow = m0 + wv * 32 + lc;
    const int zsr = t >> 1, zss = (t & 1) * 16;   // phase-A staging coords

    for (int i = t; i < NC; i += 256) lCn[i] = cnorm[i];

    // ===================== Phase A: z_e (two M-halves, sequential) ========
#define Z_LD(kt_) { \
        const float4* p = (const float4*)(Z + (size_t)(m0 + zsr) * DIN + (kt_) * 32 + zss); \
        zf[0] = p[0]; zf[1] = p[1]; zf[2] = p[2]; zf[3] = p[3]; }
#define Z_WR(b_) { \
        short8_t h0, l0, h1, l1; \
        cvt8_hl(zf[0], zf[1], h0, l0); cvt8_hl(zf[2], zf[3], h1, l1); \
        *(short8_t*)&aH[b_][zsr * 40 + zss]     = h0; \
        *(short8_t*)&aH[b_][zsr * 40 + zss + 8] = h1; \
        *(short8_t*)&aL[b_][zsr * 40 + zss]     = l0; \
        *(short8_t*)&aL[b_][zsr * 40 + zss + 8] = l1; }
#define WD_LD(kt_, H_, L_) { \
        H_[0] = *(const short8_t*)(WdHr + (kt_) * 32 + hi * 8); \
        H_[1] = *(const short8_t*)(WdHr + (kt_) * 32 + 16 + hi * 8); \
        L_[0] = *(const short8_t*)(WdLr + (kt_) * 32 + hi * 8); \
        L_[1] = *(const short8_t*)(WdLr + (kt_) * 32 + 16 + hi * 8); }

    for (int mh = 0; mh < 2; ++mh) {
        const int nb = mh * 128;
        const int wdrow = nb + wv * 32 + lc;
        const u16* WdHr = WdH + (size_t)wdrow * DIN;
        const u16* WdLr = WdL + (size_t)wdrow * DIN;

        float4 zf[4];
        short8_t wh[2], wl[2], nwh[2], nwl[2];
        Z_LD(0);
        WD_LD(0, wh, wl);
        __syncthreads();          // prior LDS consumers done
        Z_WR(0);
        __syncthreads();

        f32x16_t acc[4];
#pragma unroll
        for (int s = 0; s < 4; ++s)
#pragma unroll
            for (int r = 0; r < 16; ++r) acc[s][r] = 0.f;

        for (int kt = 0; kt < 16; ++kt) {
            if (kt < 15) { Z_LD(kt + 1); WD_LD(kt + 1, nwh, nwl); }
            const int buf = kt & 1;
            __builtin_amdgcn_s_setprio(1);
#pragma unroll
            for (int ks = 0; ks < 2; ++ks) {
#pragma unroll
                for (int s = 0; s < 4; ++s) {
                    const int lo = (s * 32 + lc) * 40 + ks * 16 + hi * 8;
                    short8_t zh = *(const short8_t*)&aH[buf][lo];
                    short8_t zl = *(const short8_t*)&aL[buf][lo];
                    acc[s] = __builtin_amdgcn_mfma_f32_32x32x16_bf16(zh, wh[ks], acc[s], 0, 0, 0);
                    acc[s] = __builtin_amdgcn_mfma_f32_32x32x16_bf16(zh, wl[ks], acc[s], 0, 0, 0);
                    acc[s] = __builtin_amdgcn_mfma_f32_32x32x16_bf16(zl, wh[ks], acc[s], 0, 0, 0);
                }
            }
            __builtin_amdgcn_s_setprio(0);
            if (kt < 15) {
                __syncthreads();
                Z_WR((kt + 1) & 1);
                wh[0] = nwh[0]; wh[1] = nwh[1];
                wl[0] = nwl[0]; wl[1] = nwl[1];
                __syncthreads();
            }
        }
        // epilogue: acc[s][r] -> zeF[m0 + s*32+(r&3)+8*(r>>2)+4*hi][nb+wv*32+lc]
#pragma unroll
        for (int s = 0; s < 4; ++s)
#pragma unroll
            for (int r = 0; r < 16; ++r) {
                const int zr = m0 + s * 32 + (r & 3) + 8 * (r >> 2) + 4 * hi;
                zeF[(size_t)zr * DE + nb + wv * 32 + lc] = acc[s][r];
            }
    }
#undef Z_LD
#undef Z_WR
#undef WD_LD
    __syncthreads();   // drain zeF stores + free LDS for phase B

    // ===================== Phase B: argmin (async staged) =================
    short8_t bh[16], bl[16];
    float rn = 0.f;
#pragma unroll
    for (int c = 0; c < 16; ++c) {
        const float4* zp = (const float4*)(zeF + (size_t)zrow * DE + c * 16 + hi * 8);
        float4 a = zp[0], b = zp[1];
        rn += a.x*a.x + a.y*a.y + a.z*a.z + a.w*a.w
            + b.x*b.x + b.y*b.y + b.z*b.z + b.w*b.w;
        cvt8_hl(a, b, bh[c], bl[c]);
    }
    rn += __shfl_xor(rn, 32, 64);

    // async staging: granule p = t + j*256 -> LDS byte p*16 (linear per wave,
    // unpadded [128][32]-u16 rows); global source uses swizzled g_log.
#define STAGE_GL(ct_, kt_) { \
        _Pragma("unroll") \
        for (int j = 0; j < 2; ++j) { \
            int p = t + j * 256; \
            int row = p >> 2, gp = p & 3; \
            int gl = gp ^ ((row >> 1) & 3); \
            size_t off = (size_t)((ct_) * 128 + row) * DE + (kt_) * 32 + gl * 8; \
            gl_lds16(embH + off, &aH[bufn][p * 8]); \
            gl_lds16(embL + off, &aL[bufn][p * 8]); \
        } }

    const int rho = (lc >> 1) & 3;   // read-side swizzle (uniform over s)

    float best = 3.4e38f, sec = 3.4e38f; int bidx = 0;
    {
        const int bufn = 0;
        STAGE_GL(0, 0);
    }
    for (int ct = 0; ct < 8; ++ct) {
        f32x16_t acc[4];
#pragma unroll
        for (int s = 0; s < 4; ++s)
#pragma unroll
            for (int r = 0; r < 16; ++r) acc[s][r] = 0.f;
#pragma unroll
        for (int kt = 0; kt < 8; ++kt) {
            __syncthreads();      // drains vmcnt -> buffer (kt&1) ready
            {
                const int bufn = (kt + 1) & 1;
                if (kt < 7)      STAGE_GL(ct, kt + 1)
                else if (ct < 7) STAGE_GL(ct + 1, 0)
            }
            const int buf = kt & 1;
            __builtin_amdgcn_s_setprio(1);
#pragma unroll
            for (int ks = 0; ks < 2; ++ks) {
                const int c = kt * 2 + ks;
#pragma unroll
                for (int s = 0; s < 4; ++s) {
                    const int lo = (s * 32 + lc) * 32 + (((ks * 2 + hi) ^ rho) << 3);
                    short8_t ah = *(const short8_t*)&aH[buf][lo];
                    short8_t al = *(const short8_t*)&aL[buf][lo];
                    acc[s] = __builtin_amdgcn_mfma_f32_32x32x16_bf16(ah, bh[c], acc[s], 0, 0, 0);
                    acc[s] = __builtin_amdgcn_mfma_f32_32x32x16_bf16(ah, bl[c], acc[s], 0, 0, 0);
                    acc[s] = __builtin_amdgcn_mfma_f32_32x32x16_bf16(al, bh[c], acc[s], 0, 0, 0);
                }
            }
            __builtin_amdgcn_s_setprio(0);
        }
#pragma unroll
        for (int s = 0; s < 4; ++s)
#pragma unroll
            for (int r = 0; r < 16; ++r) {
                const int cidx = ct * 128 + s * 32 + (r & 3) + 8 * (r >> 2) + 4 * hi;
                float d = fmaf(-2.f, acc[s][r], lCn[cidx]);
                bool lt = d < best;
                sec  = lt ? best : fminf(sec, d);
                best = lt ? d : best;
                bidx = lt ? cidx : bidx;
            }
    }
#undef STAGE_GL
    {
        float ob = __shfl_xor(best, 32, 64);
        float os = __shfl_xor(sec,  32, 64);
        int   oi = __shfl_xor(bidx, 32, 64);
        float ns = fminf(fminf(sec, os), fmaxf(best, ob));
        if (ob < best) { best = ob; bidx = oi; }
        sec = ns;
    }
    if (lane < 32) {
        codew[zrow] = (u16)bidx;
        out_codef[zrow] = (float)bidx;
        if (sec - best < 0.02f) {
            int pos = atomicAdd(flagcnt, 1);
            if (pos < FLAGCAP) flaglist[pos] = zrow;
        }
        lLoss[wv * 32 + lc] = rn + best;
    }
    __syncthreads();
    for (int str = 64; str > 0; str >>= 1) {
        if (t < str) lLoss[t] += lLoss[t + str];
        __syncthreads();
    }
    if (t == 0) atomicAdd(&lossacc[m0 >> 12], lLoss[0]);
}

// ---------------------------------------------------------------------------
// K2b: f64 exact re-argmin for flagged rows; updates codew AND out_code.
// Block 0 also emits the loss outputs (lossacc is final after k_fz).
// ---------------------------------------------------------------------------
__global__ __launch_bounds__(256) void k_refine(
        const float* __restrict__ Z, const float* __restrict__ Wd,
        const float* __restrict__ emb,
        const int* __restrict__ flaglist, const int* __restrict__ flagcnt,
        u16* __restrict__ codew, float* __restrict__ out_codef,
        const float* __restrict__ lossacc,
        float* __restrict__ out_commit, float* __restrict__ out_codebook) {
    __shared__ float  lz[DIN];
    __shared__ double lze[DE];
    __shared__ double ld[256];
    __shared__ int    li[256];
    int t = threadIdx.x;
    if (blockIdx.x == 0 && t < 16) {
        float v = lossacc[t] * (1.f / 1048576.f);
        out_commit[t] = v; out_codebook[t] = v;
    }
    int n = *flagcnt; if (n < 0) n = 0; if (n > FLAGCAP) n = FLAGCAP;
    for (int f = blockIdx.x; f < n; f += gridDim.x) {
        int row = flaglist[f] & (M_ - 1);
        __syncthreads();
        for (int i = t; i < DIN; i += 256) lz[i] = Z[(size_t)row * DIN + i];
        __syncthreads();
        double a = 0.0;
        const float* wr = Wd + (size_t)t * DIN;
        for (int k = 0; k < DIN; ++k) a += (double)lz[k] * (double)wr[k];
        lze[t] = a;
        __syncthreads();
        double bd = 1e300; int bi = 0;
        for (int cc = 0; cc < 4; ++cc) {
            int c = cc * 256 + t;
            const float* cr = emb + (size_t)c * DE;
            double s = 0.0;
            for (int e = 0; e < DE; ++e) {
                double diff = lze[e] - (double)cr[e];
                s += diff * diff;
            }
            if (s < bd) { bd = s; bi = c; }
        }
        ld[t] = bd; li[t] = bi;
        __syncthreads();
        for (int str = 128; str > 0; str >>= 1) {
            if (t < str) {
                double od = ld[t + str]; int oi = li[t + str];
                if (od < ld[t] || (od == ld[t] && oi < li[t])) { ld[t] = od; li[t] = oi; }
            }
            __syncthreads();
        }
        if (t == 0) { codew[row] = (u16)li[0]; out_codef[row] = (float)li[0]; }
        __syncthreads();
    }
}

// ---------------------------------------------------------------------------
// K3 (P path): z_q_out[row] = P[code[row]] — pure coalesced gather.
// Reads ONLY P (d_ws) and out_code (outside the z_q write region).
// ---------------------------------------------------------------------------
__global__ __launch_bounds__(256) void k_gather(
        const float* __restrict__ P, const float* __restrict__ out_code,
        float* __restrict__ out) {
    const int g = blockIdx.x * 256 + threadIdx.x;     // 524288 threads
    const float4* P4 = (const float4*)P;
    float4* O4 = (float4*)out;
    for (int u = g; u < M_ * 128; u += 524288) {
        const int row = u >> 7, seg = u & 127;
        const int c = (int)out_code[row] & (NC - 1);
        O4[(size_t)row * 128 + seg] = P4[(size_t)c * 128 + seg];
    }
}

// ---------------------------------------------------------------------------
// K3 (fallback, ws too small): z_q_out = emb[code] @ Wu^T, single bf16 term.
// ---------------------------------------------------------------------------
__global__ __launch_bounds__(512) void k_gemm3(
        const float* __restrict__ emb, const float* __restrict__ Wu,
        const float* __restrict__ out_code, float* __restrict__ out) {
    __shared__ __align__(16) u16 gA[128 * 264];   // 67.6 KB
    const int bz = blockIdx.x >> 1, nh = blockIdx.x & 1;
    const int m0 = bz * 128;
    const int t = threadIdx.x, lane = t & 63, wv = t >> 6;
    const int lr = lane & 15, lg = lane >> 4;
    {
        const int row = t >> 2, seg = (t & 3) * 64;
        const int code = (int)out_code[m0 + row] & (NC - 1);
        const float* src = emb + (size_t)code * DE + seg;
#pragma unroll
        for (int j = 0; j < 8; ++j) {
            const float4* p = (const float4*)(src + j * 8);
            *(short8_t*)&gA[row * 264 + seg + j * 8] = cvt8(p[0], p[1]);
        }
    }
    __syncthreads();

    const int nbase = nh * 256 + wv * 32;
    f32x4_t acc[8][2];
#pragma unroll
    for (int i = 0; i < 8; ++i)
#pragma unroll
        for (int j = 0; j < 2; ++j) acc[i][j] = (f32x4_t){0.f, 0.f, 0.f, 0.f};

#pragma unroll
    for (int kt = 0; kt < 8; ++kt) {
        const int k0 = kt * 32 + lg * 8;
        short8_t b0, b1;
        {
            const float4* p = (const float4*)(Wu + (size_t)(nbase + lr) * DE + k0);
            b0 = cvt8(p[0], p[1]);
            const float4* q = (const float4*)(Wu + (size_t)(nbase + 16 + lr) * DE + k0);
            b1 = cvt8(q[0], q[1]);
        }
#pragma unroll
        for (int mi = 0; mi < 8; ++mi) {
            short8_t a = *(const short8_t*)&gA[(mi * 16 + lr) * 264 + k0];
            acc[mi][0] = __builtin_amdgcn_mfma_f32_16x16x32_bf16(a, b0, acc[mi][0], 0, 0, 0);
            acc[mi][1] = __builtin_amdgcn_mfma_f32_16x16x32_bf16(a, b1, acc[mi][1], 0, 0, 0);
        }
    }
#pragma unroll
    for (int mi = 0; mi < 8; ++mi)
#pragma unroll
        for (int reg = 0; reg < 4; ++reg) {
            const int zr = m0 + mi * 16 + lg * 4 + reg;
            out[(size_t)zr * DIN + nbase + lr]      = acc[mi][0][reg];
            out[(size_t)zr * DIN + nbase + 16 + lr] = acc[mi][1][reg];
        }
}

// ---------------------------------------------------------------------------
extern "C" void kernel_launch(void* const* d_in, const int* in_sizes, int n_in,
                              void* d_out, int out_size, void* d_ws, size_t ws_size,
                              hipStream_t stream) {
    const float* Z   = (const float*)d_in[0];   // [16,4096,512] f32
    const float* E   = (const float*)d_in[1];   // [1024,256]    f32
    const float* Wd  = (const float*)d_in[2];   // [256,512]     f32
    const float* Wu  = (const float*)d_in[3];   // [512,256]     f32

    float* out       = (float*)d_out;           // f32 outputs, concat
    float* out_zq    = out;                     // [0, 33554432)
    float* out_com   = out + 33554432;          // 16
    float* out_cb    = out + 33554448;          // 16
    float* out_code  = out + 33554464;          // 65536
    float* out_ze    = out + 33620000;          // 16,777,216

    char* scr = (char*)d_out;
    u16*   embH     = (u16*)  (scr + 0);          // 524,288 B
    u16*   embL     = (u16*)  (scr + 524288);     // 524,288 B
    u16*   WdH      = (u16*)  (scr + 1048576);    // 262,144 B
    u16*   WdL      = (u16*)  (scr + 1310720);    // 262,144 B
    float* cnorm    = (float*)(scr + 1572864);    //   4,096 B
    u16*   codew    = (u16*)  (scr + 1839104);    // 131,072 B
    int*   flaglist = (int*)  (scr + 1970176);    //  65,536 B
    int*   flagcnt  = (int*)  (scr + 2035712);    //      64 B
    float* lossacc  = (float*)(scr + 2035776);    //      64 B
    (void)in_sizes; (void)n_in; (void)out_size;

    const bool useP = (ws_size >= (size_t)NC * DIN * sizeof(float));  // 2 MB
    float* P = (float*)d_ws;

    k_init  <<<256,  256, 0, stream>>>(E, Wd, embH, embL, WdH, WdL, cnorm,
                                       lossacc, flagcnt);
    if (useP)
        k_pup <<<128, 256, 0, stream>>>(E, Wu, P);
    k_fz    <<<512,  256, 0, stream>>>(Z, WdH, WdL, embH, embL, cnorm, out_ze,
                                       codew, out_code, flaglist, flagcnt, lossacc);
    k_refine<<<128,  256, 0, stream>>>(Z, Wd, E, flaglist, flagcnt, codew, out_code,
                                       lossacc, out_com, out_cb);
    if (useP)
        k_gather<<<2048, 256, 0, stream>>>(P, out_code, out_zq);
    else
        k_gemm3 <<<1024, 512, 0, stream>>>(E, Wu, out_code, out_zq);
}